// Round 3
// baseline (321.969 us; speedup 1.0000x reference)
//
#include <hip/hip_runtime.h>
#include <math.h>

#define BB 8
#define TQ 256
#define TV 512
#define DD 128
#define TI 4
#define NT 1024
#define LN_EPS 1e-3f

typedef float f4 __attribute__((ext_vector_type(4)));

static __device__ __forceinline__ f4 vfma_s(f4 a, float s, f4 c) {
    f4 r;
    r[0] = fmaf(a[0], s, c[0]); r[1] = fmaf(a[1], s, c[1]);
    r[2] = fmaf(a[2], s, c[2]); r[3] = fmaf(a[3], s, c[3]);
    return r;
}
static __device__ __forceinline__ f4 vfma_v(f4 a, f4 b, f4 c) {
    f4 r;
    r[0] = fmaf(a[0], b[0], c[0]); r[1] = fmaf(a[1], b[1], c[1]);
    r[2] = fmaf(a[2], b[2], c[2]); r[3] = fmaf(a[3], b[3], c[3]);
    return r;
}
static __device__ __forceinline__ f4 vmul_s(f4 a, float s) {
    f4 r; r[0] = a[0]*s; r[1] = a[1]*s; r[2] = a[2]*s; r[3] = a[3]*s; return r;
}
static __device__ __forceinline__ f4 vrcp(f4 a) {
    f4 r;
    r[0] = __builtin_amdgcn_rcpf(a[0]); r[1] = __builtin_amdgcn_rcpf(a[1]);
    r[2] = __builtin_amdgcn_rcpf(a[2]); r[3] = __builtin_amdgcn_rcpf(a[3]);
    return r;
}

// ---------------- Kernel 1: F = exp(2*context) ----------------
__global__ __launch_bounds__(256) void prep_kernel(const float* __restrict__ ctx,
                                                   float* __restrict__ F) {
    int idx = blockIdx.x * 256 + threadIdx.x;
    f4 c = ((const f4*)ctx)[idx];
    f4 r;
#pragma unroll
    for (int k = 0; k < 4; ++k) r[k] = __expf(2.0f * c[k]);
    ((f4*)F)[idx] = r;
}

// ---------------- Kernel 2: fused scores + softmax + PV + residual + LN ----
// 1024 threads (16 waves), TI=4 rows/block, grid 512 -> 2 blocks/CU (32 waves/CU).
// score'[j] = sum_d (-2 s_d)/(1 + E[i,d]*F[j,d]); quad-merged reciprocals.
// Thread t: jj = t&255 owns j in {jj, jj+256}; q = t>>8 owns d in [32q, 32q+32).
__global__ __launch_bounds__(NT, 8) void attn_kernel(const float* __restrict__ x,
                                                     const float* __restrict__ ctx,
                                                     const float* __restrict__ scale,
                                                     const float* __restrict__ gamma,
                                                     const float* __restrict__ beta,
                                                     const float* __restrict__ F,
                                                     float* __restrict__ out) {
    __shared__ float xs[TI * DD];       // residual rows              2KB
    __shared__ f4    txE[DD];           // [d] -> e^{2x} for 4 rows   2KB
    __shared__ f4    s2n4[DD / 4];      // -2*scale packed by d-quad  0.5KB
    __shared__ f4    pacc[3][256][2];   // partial scores q=1..3      24KB
    __shared__ f4    wT[TV];            // softmax weights per j      8KB
    __shared__ float red[8][TI][DD];    // PV partials                16KB
    __shared__ f4    mred[4];
    __shared__ f4    sred[4];
    __shared__ float lnred[8][2];

    const int t  = threadIdx.x;
    const int bg = blockIdx.x;
    // bijective XCD swizzle: XCD k owns batch k (ctx+F 0.5MB L2-resident per XCD)
    const int wg   = (bg & 7) * 64 + (bg >> 3);
    const int b    = wg >> 6;
    const int i0   = (wg & 63) * TI;
    const int wv   = t >> 6;
    const int lane = t & 63;

    // ---- setup ----
    if (t < TI * DD) {
        int r = t >> 7, d = t & 127;
        float v = x[(size_t)(b * TQ + i0 + r) * DD + d];
        xs[t] = v;
        txE[d][r] = __expf(2.0f * v);
    }
    if (t >= 512 && t < 512 + DD / 4) {
        f4 sv = ((const f4*)scale)[t - 512];
        s2n4[t - 512] = vmul_s(sv, -2.0f);
    }
    __syncthreads();

    // ---- phase 1: scores, quad-merged rcp ----
    const int jj = t & 255;
    const int q  = t >> 8;
    const int d0 = q * 32;
    const f4 one = {1.f, 1.f, 1.f, 1.f};

    auto do_j = [&](int j, f4& a) {
        const f4* Fp = (const f4*)(F + (size_t)(b * TV + j) * DD + d0);
#pragma unroll
        for (int dq = 0; dq < 8; ++dq) {
            f4 Fv = Fp[dq];
            const int dbase = d0 + dq * 4;
            f4 E0 = txE[dbase + 0], E1 = txE[dbase + 1];
            f4 E2 = txE[dbase + 2], E3 = txE[dbase + 3];
            f4 sn = s2n4[dbase >> 2];
            f4 da = vfma_s(E0, Fv[0], one);
            f4 db = vfma_s(E1, Fv[1], one);
            f4 ab = da * db;
            f4 u0 = vmul_s(db, sn[0]);
            u0 = vfma_s(da, sn[1], u0);
            f4 dc = vfma_s(E2, Fv[2], one);
            f4 de = vfma_s(E3, Fv[3], one);
            f4 ce = dc * de;
            f4 u1 = vmul_s(de, sn[2]);
            u1 = vfma_s(dc, sn[3], u1);
            f4 abce = ab * ce;
            f4 num = u0 * ce;
            num = vfma_v(u1, ab, num);
            f4 rv = vrcp(abce);
            a = vfma_v(num, rv, a);
        }
    };
    f4 acc0 = {0.f, 0.f, 0.f, 0.f}, acc1 = {0.f, 0.f, 0.f, 0.f};
    do_j(jj, acc0);
    do_j(jj + 256, acc1);

    if (q > 0) { pacc[q - 1][jj][0] = acc0; pacc[q - 1][jj][1] = acc1; }
    __syncthreads();

    // ---- phase 2: softmax (q==0 threads: waves 0..3), single-barrier ----
    f4 m, e0, e1;
    if (q == 0) {
#pragma unroll
        for (int p = 0; p < 3; ++p) {
            f4 o0 = pacc[p][jj][0], o1 = pacc[p][jj][1];
#pragma unroll
            for (int r = 0; r < TI; ++r) { acc0[r] += o0[r]; acc1[r] += o1[r]; }
        }
#pragma unroll
        for (int r = 0; r < TI; ++r) m[r] = fmaxf(acc0[r], acc1[r]);
#pragma unroll
        for (int off = 32; off > 0; off >>= 1) {
#pragma unroll
            for (int r = 0; r < TI; ++r) m[r] = fmaxf(m[r], __shfl_xor(m[r], off));
        }
#pragma unroll
        for (int r = 0; r < TI; ++r) {
            e0[r] = __expf(acc0[r] - m[r]);
            e1[r] = __expf(acc1[r] - m[r]);
        }
        f4 s = e0 + e1;
#pragma unroll
        for (int off = 32; off > 0; off >>= 1) {
#pragma unroll
            for (int r = 0; r < TI; ++r) s[r] += __shfl_xor(s[r], off);
        }
        if (lane == 0) { mred[wv] = m; sred[wv] = s; }
    }
    __syncthreads();
    if (q == 0) {
        f4 M = mred[0];
#pragma unroll
        for (int w = 1; w < 4; ++w) {
            f4 o = mred[w];
#pragma unroll
            for (int r = 0; r < TI; ++r) M[r] = fmaxf(M[r], o[r]);
        }
        f4 S = {0.f, 0.f, 0.f, 0.f};
#pragma unroll
        for (int w = 0; w < 4; ++w) {
            f4 mw = mred[w], sw = sred[w];
#pragma unroll
            for (int r = 0; r < TI; ++r) S[r] += sw[r] * __expf(mw[r] - M[r]);
        }
        f4 w0, w1;
#pragma unroll
        for (int r = 0; r < TI; ++r) {
            float inv = __expf(m[r] - M[r]) * __builtin_amdgcn_rcpf(S[r]);
            w0[r] = e0[r] * inv;
            w1[r] = e1[r] * inv;
        }
        wT[jj] = w0;
        wT[jj + 256] = w1;
    }
    __syncthreads();

    // ---- phase 3: attn_out[r][d] = sum_j w[r][j]*ctx[j][d]; 8 j-groups of 64 ----
    {
        const int g = t >> 7;
        const int d = t & 127;
        const float* cp = ctx + (size_t)(b * TV + g * 64) * DD + d;
        f4 p = {0.f, 0.f, 0.f, 0.f};
#pragma unroll 4
        for (int js = 0; js < 64; ++js) {
            f4 wj = wT[g * 64 + js];          // LDS broadcast
            float cv = cp[(size_t)js * DD];   // coalesced
            p = vfma_s(wj, cv, p);            // wait: want p[r] += wj[r]*cv
        }
#pragma unroll
        for (int r = 0; r < TI; ++r) red[g][r][d] = p[r];
    }
    __syncthreads();

    // ---- phase 4: reduce partials, residual, LayerNorm, store ----
    {
        const int r = t >> 7;
        const int d = t & 127;
        float y = 0.f;
        if (t < 512) {
            float attn = 0.f;
#pragma unroll
            for (int g = 0; g < 8; ++g) attn += red[g][r][d];
            y = xs[r * DD + d] + attn;
        }
        float s1 = y, s2 = y * y;
#pragma unroll
        for (int off = 32; off > 0; off >>= 1) {
            s1 += __shfl_xor(s1, off);
            s2 += __shfl_xor(s2, off);
        }
        if (lane == 0 && wv < 8) { lnred[wv][0] = s1; lnred[wv][1] = s2; }
        __syncthreads();
        if (t < 512) {
            float S1 = lnred[2 * r][0] + lnred[2 * r + 1][0];
            float S2 = lnred[2 * r][1] + lnred[2 * r + 1][1];
            float mu  = S1 * (1.0f / 128.0f);
            float var = S2 * (1.0f / 128.0f) - mu * mu;
            float inv = rsqrtf(var + LN_EPS);
            out[(size_t)(b * TQ + i0 + r) * DD + d] = gamma[d] * (y - mu) * inv + beta[d];
        }
    }
}

extern "C" void kernel_launch(void* const* d_in, const int* in_sizes, int n_in,
                              void* d_out, int out_size, void* d_ws, size_t ws_size,
                              hipStream_t stream) {
    const float* x     = (const float*)d_in[0];
    const float* ctx   = (const float*)d_in[1];
    const float* scale = (const float*)d_in[2];
    const float* gamma = (const float*)d_in[3];
    const float* beta  = (const float*)d_in[4];
    float* out = (float*)d_out;

    float* F = (float*)d_ws;   // B*TV*D floats = 2MB

    prep_kernel<<<(BB * TV * DD / 4) / 256, 256, 0, stream>>>(ctx, F);
    attn_kernel<<<(BB * TQ) / TI, NT, 0, stream>>>(x, ctx, scale, gamma, beta, F, out);
}

// Round 5
// 96.252 us; speedup vs baseline: 3.3450x; 3.3450x over previous
//
#include <hip/hip_runtime.h>
#include <math.h>

#define BB 8
#define TQ 256
#define TV 512
#define DD 128
#define TI 4
#define NT 1024
#define LN_EPS 1e-3f

typedef float f4 __attribute__((ext_vector_type(4)));

// ws float layout:
//  FT  [BB][DD][TV]      : transposed exp(2*ctx)            (2MB)
//  Epk [BB*64][DD] (f4)  : exp(2*x) packed 4-row groups     (1MB)
//  sn4 [DD/4] (f4)       : -2*scale                         (512B)
#define FT_OFF   0
#define EPK_OFF  (BB * DD * TV)
#define SN_OFF   (EPK_OFF + BB * TQ * DD)

static __device__ __forceinline__ f4 vfma_s(f4 a, float s, f4 c) {
    f4 r;
    r[0] = fmaf(a[0], s, c[0]); r[1] = fmaf(a[1], s, c[1]);
    r[2] = fmaf(a[2], s, c[2]); r[3] = fmaf(a[3], s, c[3]);
    return r;
}
static __device__ __forceinline__ f4 vfma_v(f4 a, f4 b, f4 c) {
    f4 r;
    r[0] = fmaf(a[0], b[0], c[0]); r[1] = fmaf(a[1], b[1], c[1]);
    r[2] = fmaf(a[2], b[2], c[2]); r[3] = fmaf(a[3], b[3], c[3]);
    return r;
}
static __device__ __forceinline__ f4 vmul_s(f4 a, float s) {
    f4 r; r[0] = a[0]*s; r[1] = a[1]*s; r[2] = a[2]*s; r[3] = a[3]*s; return r;
}
static __device__ __forceinline__ f4 vrcp(f4 a) {
    f4 r;
    r[0] = __builtin_amdgcn_rcpf(a[0]); r[1] = __builtin_amdgcn_rcpf(a[1]);
    r[2] = __builtin_amdgcn_rcpf(a[2]); r[3] = __builtin_amdgcn_rcpf(a[3]);
    return r;
}

// ---------------- prep: blocks 0..63 transpose-F, 64..319 pack-E (+sn) ------
__global__ __launch_bounds__(256) void prep_kernel(const float* __restrict__ ctx,
                                                   const float* __restrict__ x,
                                                   const float* __restrict__ scale,
                                                   float* __restrict__ ws) {
    float* FT  = ws + FT_OFF;
    f4*    Epk = (f4*)(ws + EPK_OFF);
    f4*    sn4 = (f4*)(ws + SN_OFF);
    const int t = threadIdx.x;
    const int blk = blockIdx.x;
    if (blk < 64) {
        __shared__ float tile[64][DD + 1];   // +1 pad: conflict-free transposed read
        const int b = blk >> 3, j0 = (blk & 7) * 64;
        const f4* c4 = (const f4*)ctx;
#pragma unroll
        for (int k = 0; k < 8; ++k) {
            int idx = k * 256 + t;                 // 0..2047
            int jr = idx >> 5, d4 = idx & 31;
            f4 c = c4[(size_t)(b * TV + j0 + jr) * (DD / 4) + d4];
#pragma unroll
            for (int i = 0; i < 4; ++i) tile[jr][d4 * 4 + i] = __expf(2.0f * c[i]);
        }
        __syncthreads();
        const int jl = t & 63, dh = t >> 6;        // dh 0..3
#pragma unroll
        for (int dd = 0; dd < 32; ++dd) {
            int d = dh * 32 + dd;
            FT[(size_t)(b * DD + d) * TV + j0 + jl] = tile[jl][d];
        }
    } else {
        int idx = (blk - 64) * 256 + t;            // 0..65535
        int d = idx & 127, ig = idx >> 7;          // ig = global 4-row group 0..511
        f4 e;
#pragma unroll
        for (int r = 0; r < 4; ++r)
            e[r] = __expf(2.0f * x[(size_t)(ig * 4 + r) * DD + d]);
        Epk[idx] = e;
        if (blk == 64 && t < DD / 4) {
            f4 s = ((const f4*)scale)[t];
            f4 o; o[0] = -2.f*s[0]; o[1] = -2.f*s[1]; o[2] = -2.f*s[2]; o[3] = -2.f*s[3];
            sn4[t] = o;
        }
    }
}

// ---------------- attn: 1024 thr, TI=4 rows, grid 512 (2 blocks/CU) ---------
// score'[j] = sum_d (-2 s_d)/(1 + E[i,d]*F[j,d]); pair-merged reciprocals.
// Thread: j = t&511 (lane-consecutive -> coalesced FT reads), h = t>>9 d-half.
// E/sn via wave-uniform loads -> SGPRs (zero LDS in hot loop).
__global__ __launch_bounds__(NT, 8) void attn_kernel(const float* __restrict__ x,
                                                     const float* __restrict__ ctx,
                                                     const float* __restrict__ gamma,
                                                     const float* __restrict__ beta,
                                                     const float* __restrict__ ws,
                                                     float* __restrict__ out) {
    __shared__ f4    pacc[TV];         // 8KB  h=1 partial scores
    __shared__ f4    wT[TV];           // 8KB  softmax weights
    __shared__ float red[8][TI][DD];   // 16KB PV partials
    __shared__ f4    mred[8], sred[8];
    __shared__ float lnred[8][2];

    const float* FT  = ws + FT_OFF;
    const f4*    Epk = (const f4*)(ws + EPK_OFF);
    const f4*    sn4 = (const f4*)(ws + SN_OFF);

    const int t  = threadIdx.x;
    const int bg = blockIdx.x;
    const int wg   = (bg & 7) * 64 + (bg >> 3);   // XCD k owns batch k
    const int b    = wg >> 6;
    const int ig   = wg & 63;
    const int i0   = ig * TI;
    const int wv   = t >> 6;
    const int lane = t & 63;

    const int j = t & 511;
    const int h = t >> 9;

    // ---- phase 1: scores (pair-merged rcp, SGPR E/sn, coalesced FT) ----
    const float* Fp = FT + (size_t)(b * DD + h * 64) * TV + j;
    const f4*    Ep = Epk + (size_t)(b * 64 + ig) * DD + h * 64;   // uniform
    const f4 one = {1.f, 1.f, 1.f, 1.f};
    f4 acc = {0.f, 0.f, 0.f, 0.f};
#pragma unroll 4
    for (int dq = 0; dq < 16; ++dq) {
        f4 sq = sn4[h * 16 + dq];                  // s_load_dwordx4
        f4 e0 = Ep[dq * 4 + 0], e1 = Ep[dq * 4 + 1];
        f4 e2 = Ep[dq * 4 + 2], e3 = Ep[dq * 4 + 3];
        float f0 = Fp[(size_t)(dq * 4 + 0) * TV];  // coalesced 256B/wave
        float f1 = Fp[(size_t)(dq * 4 + 1) * TV];
        float f2 = Fp[(size_t)(dq * 4 + 2) * TV];
        float f3 = Fp[(size_t)(dq * 4 + 3) * TV];
        // pair (d, d+1)
        f4 da = vfma_s(e0, f0, one);
        f4 db = vfma_s(e1, f1, one);
        f4 pr = da * db;
        f4 nu = vmul_s(db, sq[0]);
        nu = vfma_s(da, sq[1], nu);
        acc = vfma_v(nu, vrcp(pr), acc);
        // pair (d+2, d+3)
        f4 dc = vfma_s(e2, f2, one);
        f4 de = vfma_s(e3, f3, one);
        f4 p2 = dc * de;
        f4 n2 = vmul_s(de, sq[2]);
        n2 = vfma_s(dc, sq[3], n2);
        acc = vfma_v(n2, vrcp(p2), acc);
    }
    if (h == 1) pacc[j] = acc;
    __syncthreads();
    if (h == 0) {
        f4 o = pacc[j];
#pragma unroll
        for (int r = 0; r < TI; ++r) acc[r] += o[r];
    }

    // ---- phase 2: block softmax over 512 j (h==0 waves 0..7 own scores) ----
    f4 m = acc;
#pragma unroll
    for (int off = 32; off > 0; off >>= 1) {
#pragma unroll
        for (int r = 0; r < TI; ++r) m[r] = fmaxf(m[r], __shfl_xor(m[r], off));
    }
    if (h == 0 && lane == 0) mred[wv] = m;
    __syncthreads();
    f4 M = mred[0];
#pragma unroll
    for (int w = 1; w < 8; ++w) {
        f4 o = mred[w];
#pragma unroll
        for (int r = 0; r < TI; ++r) M[r] = fmaxf(M[r], o[r]);
    }
    f4 e;
#pragma unroll
    for (int r = 0; r < TI; ++r) e[r] = __expf(acc[r] - M[r]);
    f4 s = e;
#pragma unroll
    for (int off = 32; off > 0; off >>= 1) {
#pragma unroll
        for (int r = 0; r < TI; ++r) s[r] += __shfl_xor(s[r], off);
    }
    if (h == 0 && lane == 0) sred[wv] = s;
    __syncthreads();
    f4 S = sred[0];
#pragma unroll
    for (int w = 1; w < 8; ++w) {
        f4 o = sred[w];
#pragma unroll
        for (int r = 0; r < TI; ++r) S[r] += o[r];
    }
    if (h == 0) {
        f4 w4;
#pragma unroll
        for (int r = 0; r < TI; ++r) w4[r] = e[r] * __builtin_amdgcn_rcpf(S[r]);
        wT[j] = w4;
    }
    __syncthreads();

    // ---- phase 3: attn_out[r][d] = sum_j w[r][j]*ctx[j][d]; 8 groups x 64 j ----
    {
        const int g = t >> 7;
        const int d = t & 127;
        const float* cp = ctx + (size_t)(b * TV + g * 64) * DD + d;
        f4 p = {0.f, 0.f, 0.f, 0.f};
#pragma unroll 4
        for (int js = 0; js < 64; ++js) {
            f4 wj = wT[g * 64 + js];          // LDS broadcast
            float cv = cp[(size_t)js * DD];   // coalesced
            p = vfma_s(wj, cv, p);
        }
#pragma unroll
        for (int r = 0; r < TI; ++r) red[g][r][d] = p[r];
    }
    __syncthreads();

    // ---- phase 4: reduce partials, residual, LayerNorm, store ----
    {
        const int r  = t >> 7;
        const int dd = t & 127;
        float y = 0.f;
        if (t < 512) {
            float attn = 0.f;
#pragma unroll
            for (int g2 = 0; g2 < 8; ++g2) attn += red[g2][r][dd];
            y = x[(size_t)(b * TQ + i0 + r) * DD + dd] + attn;
        }
        float s1 = y, s2 = y * y;
#pragma unroll
        for (int off = 32; off > 0; off >>= 1) {
            s1 += __shfl_xor(s1, off);
            s2 += __shfl_xor(s2, off);
        }
        if (lane == 0 && wv < 8) { lnred[wv][0] = s1; lnred[wv][1] = s2; }
        __syncthreads();
        if (t < 512) {
            float S1 = lnred[2 * r][0] + lnred[2 * r + 1][0];
            float S2 = lnred[2 * r][1] + lnred[2 * r + 1][1];
            float mu  = S1 * (1.0f / 128.0f);
            float var = S2 * (1.0f / 128.0f) - mu * mu;
            float inv = rsqrtf(var + LN_EPS);
            out[(size_t)(b * TQ + i0 + r) * DD + dd] = gamma[dd] * (y - mu) * inv + beta[dd];
        }
    }
}

extern "C" void kernel_launch(void* const* d_in, const int* in_sizes, int n_in,
                              void* d_out, int out_size, void* d_ws, size_t ws_size,
                              hipStream_t stream) {
    const float* x     = (const float*)d_in[0];
    const float* ctx   = (const float*)d_in[1];
    const float* scale = (const float*)d_in[2];
    const float* gamma = (const float*)d_in[3];
    const float* beta  = (const float*)d_in[4];
    float* out = (float*)d_out;
    float* ws  = (float*)d_ws;

    prep_kernel<<<320, 256, 0, stream>>>(ctx, x, scale, ws);
    attn_kernel<<<(BB * TQ) / TI, NT, 0, stream>>>(x, ctx, gamma, beta, ws, out);
}